// Round 5
// baseline (122.181 us; speedup 1.0000x reference)
//
#include <hip/hip_runtime.h>
#include <math.h>

#define B 64
#define K 16
#define J 512
#define I 128
#define SCALE 0.08838834764831845f /* 1/sqrt(128) */
#define EPSF 1e-20f
#define JC 16  /* j-chunks */
#define JCW 32 /* J / JC */

typedef __attribute__((ext_vector_type(8))) short short8;
typedef __attribute__((ext_vector_type(4))) float f32x4;

static __device__ __forceinline__ unsigned f2bf(float f) {
    union { float f; unsigned u; } v; v.f = f;
    return (v.u + 0x7FFFu + ((v.u >> 16) & 1u)) >> 16;  // RNE to bf16
}

// ---------------------------------------------------------------------------
// K1: logits via bf16 MFMA + softmax over batch + bias.
// One wave per j (proven round-3 structure). XCD-aligned j (XCD c owns
// j in [64c,64c+64)) so k1 pre-warms exactly the L2 slice k3 reads.
// Output blocked: cw2[kt][bt][j][kk][bb] for coalesced k3 staging.
// ---------------------------------------------------------------------------
__global__ __launch_bounds__(64) void k1_mfma(const float* __restrict__ x,
                                              const float* __restrict__ w,
                                              const float* __restrict__ bias,
                                              float* __restrict__ cw2) {
    __shared__ __align__(16) char lds[80 * 256];  // lx[64][256] + lw[16][256]
    char* lx = lds;
    char* lw = lds + 64 * 256;

    const int raw = blockIdx.x;                  // 0..511
    const int j = (raw & 7) * 64 + (raw >> 3);   // XCD-aligned j
    const int l = threadIdx.x;
    const int q = l & 31, hi = l >> 5;

    const float4* xs = (const float4*)x;
    const float4* wsrc = (const float4*)w;

#pragma unroll
    for (int it = 0; it < 32; ++it) {
        int b = it * 2 + hi;
        float4 v = xs[((size_t)b * J + j) * 32 + q];
        uint2 u;
        u.x = f2bf(v.x * v.x) | (f2bf(v.y * v.y) << 16);
        u.y = f2bf(v.z * v.z) | (f2bf(v.w * v.w) << 16);
        *(uint2*)(lx + b * 256 + ((q * 8) ^ ((b & 7) << 4))) = u;
    }
#pragma unroll
    for (int it = 0; it < 8; ++it) {
        int k = it * 2 + hi;
        float4 v = wsrc[((size_t)k * J + j) * 32 + q];
        uint2 u;
        u.x = f2bf(v.x * v.x) | (f2bf(v.y * v.y) << 16);
        u.y = f2bf(v.z * v.z) | (f2bf(v.w * v.w) << 16);
        *(uint2*)(lw + k * 256 + ((q * 8) ^ ((k & 7) << 4))) = u;
    }
    __syncthreads();

    const int g = l >> 4, n = l & 15;
    f32x4 acc[4];
#pragma unroll
    for (int t = 0; t < 4; ++t) acc[t] = (f32x4){0.f, 0.f, 0.f, 0.f};

#pragma unroll
    for (int s = 0; s < 4; ++s) {
        const int colb = s * 64 + g * 16;
        short8 af = *(const short8*)(lw + n * 256 + (colb ^ ((n & 7) << 4)));
#pragma unroll
        for (int t = 0; t < 4; ++t) {
            int row = t * 16 + n;
            short8 bf = *(const short8*)(lx + row * 256 + (colb ^ ((row & 7) << 4)));
            acc[t] = __builtin_amdgcn_mfma_f32_16x16x32_bf16(af, bf, acc[t], 0, 0, 0);
        }
    }

    // lane holds c_raw[m=g*4+r][b=t*16+n] in acc[t][r]
#pragma unroll
    for (int r = 0; r < 4; ++r) {
        float s0 = acc[0][r] * SCALE, s1 = acc[1][r] * SCALE;
        float s2 = acc[2][r] * SCALE, s3 = acc[3][r] * SCALE;
        float mx = fmaxf(fmaxf(s0, s1), fmaxf(s2, s3));
#pragma unroll
        for (int msk = 1; msk <= 8; msk <<= 1) mx = fmaxf(mx, __shfl_xor(mx, msk, 64));
        float e0 = expf(s0 - mx), e1 = expf(s1 - mx);
        float e2 = expf(s2 - mx), e3 = expf(s3 - mx);
        float sum = e0 + e1 + e2 + e3;
#pragma unroll
        for (int msk = 1; msk <= 8; msk <<= 1) sum += __shfl_xor(sum, msk, 64);
        float inv = 1.f / sum;
        int m = g * 4 + r;
        float bi = bias[m * J + j];
        // cw2[kt=g][bt=t*4+(n>>2)][j][kk=r][bb=n&3]
        size_t base = (size_t)g * 131072 + (size_t)j * 16 + r * 4 + (n & 3);
        cw2[base + (size_t)(0 + (n >> 2)) * 8192]  = e0 * inv + bi;
        cw2[base + (size_t)(4 + (n >> 2)) * 8192]  = e1 * inv + bi;
        cw2[base + (size_t)(8 + (n >> 2)) * 8192]  = e2 * inv + bi;
        cw2[base + (size_t)(12 + (n >> 2)) * 8192] = e3 * inv + bi;
    }
}

// ---------------------------------------------------------------------------
// K3: sp[jh][b][k][i] = sum_{j in chunk jh} x*w*c.
// 1024 blocks = 16 bt x 4 kt x 16 jh, XCD-aligned (XCD c owns chunks
// {2c,2c+1} = j in [64c,64c+64)). 4 blocks/CU (34 KB LDS, VGPR<=128).
// Thread: 4b x 4k x float4 tile; coalesced c staging; shfl pre-reduce +
// one LDS round.
// ---------------------------------------------------------------------------
__global__ __launch_bounds__(256, 4) void k3_wsum(const float* __restrict__ x,
                                                  const float* __restrict__ w,
                                                  const float* __restrict__ cw2,
                                                  float* __restrict__ sp) {
    __shared__ float cl[JCW * 16];                     // 2 KB [jl][kk][bb]
    __shared__ __align__(16) float4 red[4 * 16 * 32];  // 32 KB [w][slot][iq]

    const int raw = blockIdx.x;                 // 0..1023
    const int swz = (raw & 7) * 128 + (raw >> 3);
    const int kt = swz & 3, bt = (swz >> 2) & 15, jh = swz >> 6;
    const int j0 = jh * JCW, b0 = bt * 4, k0 = kt * 4;

    const int iq = threadIdx.x & 31;
    const int js = threadIdx.x >> 5;

    if (threadIdx.x < 128)
        ((float4*)cl)[threadIdx.x] =
            ((const float4*)(cw2 + (size_t)kt * 131072 + (size_t)bt * 8192 +
                             (size_t)j0 * 16))[threadIdx.x];
    __syncthreads();

    float4 acc[4][4];
#pragma unroll
    for (int bb = 0; bb < 4; ++bb)
#pragma unroll
        for (int kk = 0; kk < 4; ++kk) acc[bb][kk] = make_float4(0.f, 0.f, 0.f, 0.f);

#pragma unroll
    for (int it = 0; it < 4; ++it) {
        int j = j0 + js + it * 8;
        float4 xv[4], wv[4];
#pragma unroll
        for (int bb = 0; bb < 4; ++bb)
            xv[bb] = *(const float4*)(x + ((size_t)(b0 + bb) * J + j) * I + iq * 4);
#pragma unroll
        for (int kk = 0; kk < 4; ++kk)
            wv[kk] = *(const float4*)(w + ((size_t)(k0 + kk) * J + j) * I + iq * 4);
        const float* cj = cl + (js + it * 8) * 16;
#pragma unroll
        for (int kk = 0; kk < 4; ++kk) {
#pragma unroll
            for (int bb = 0; bb < 4; ++bb) {
                float c = cj[kk * 4 + bb];
                acc[bb][kk].x = fmaf(xv[bb].x * wv[kk].x, c, acc[bb][kk].x);
                acc[bb][kk].y = fmaf(xv[bb].y * wv[kk].y, c, acc[bb][kk].y);
                acc[bb][kk].z = fmaf(xv[bb].z * wv[kk].z, c, acc[bb][kk].z);
                acc[bb][kk].w = fmaf(xv[bb].w * wv[kk].w, c, acc[bb][kk].w);
            }
        }
    }

    // reduce across the two js-halves of each wave (lanes end with the sum)
#pragma unroll
    for (int bb = 0; bb < 4; ++bb)
#pragma unroll
        for (int kk = 0; kk < 4; ++kk) {
            acc[bb][kk].x += __shfl_xor(acc[bb][kk].x, 32, 64);
            acc[bb][kk].y += __shfl_xor(acc[bb][kk].y, 32, 64);
            acc[bb][kk].z += __shfl_xor(acc[bb][kk].z, 32, 64);
            acc[bb][kk].w += __shfl_xor(acc[bb][kk].w, 32, 64);
        }

    const int wv4 = threadIdx.x >> 6;
    const int hi = (threadIdx.x >> 5) & 1;
#pragma unroll
    for (int r = 0; r < 8; ++r) {
        int slot = hi * 8 + r;
        red[(wv4 * 16 + slot) * 32 + iq] = acc[slot >> 2][slot & 3];
    }
    __syncthreads();

#pragma unroll
    for (int rep = 0; rep < 2; ++rep) {
        int slot = rep * 8 + (threadIdx.x >> 5);
        float4 a = red[(0 * 16 + slot) * 32 + iq];
        float4 b = red[(1 * 16 + slot) * 32 + iq];
        float4 c = red[(2 * 16 + slot) * 32 + iq];
        float4 d = red[(3 * 16 + slot) * 32 + iq];
        float4 v = make_float4(a.x + b.x + c.x + d.x, a.y + b.y + c.y + d.y,
                               a.z + b.z + c.z + d.z, a.w + b.w + c.w + d.w);
        int bb = slot >> 2, kk = slot & 3;
        *(float4*)(sp + (((size_t)jh * B + b0 + bb) * K + k0 + kk) * I + iq * 4) = v;
    }
}

// ---------------------------------------------------------------------------
// K4: wave per (b,k): sum 16 partials, squash over i, write out. No LDS.
// ---------------------------------------------------------------------------
__global__ __launch_bounds__(256) void k4_squash(const float* __restrict__ sp,
                                                 float* __restrict__ out) {
    const int wv = threadIdx.x >> 6;
    const int lane = threadIdx.x & 63;
    const int bk = blockIdx.x * 4 + wv;       // 0..1023
    const int b = bk >> 4, k = bk & 15;

    float s0 = 0.f, s1 = 0.f;
#pragma unroll
    for (int p = 0; p < JC; ++p) {
        float2 v = *(const float2*)(sp + (((size_t)p * B + b) * K + k) * I + lane * 2);
        s0 += v.x; s1 += v.y;
    }
    float q = s0 * s0 + s1 * s1;
#pragma unroll
    for (int m = 32; m >= 1; m >>= 1) q += __shfl_xor(q, m, 64);

    float n = sqrtf(q);
    float factor = (1.0f - 1.0f / (expf(n) + EPSF)) / (n + EPSF);
    float2 o = make_float2(s0 * factor, s1 * factor);
    *(float2*)(out + ((size_t)b * K + k) * I + lane * 2) = o;
}

// ---------------------------------------------------------------------------
extern "C" void kernel_launch(void* const* d_in, const int* in_sizes, int n_in,
                              void* d_out, int out_size, void* d_ws, size_t ws_size,
                              hipStream_t stream) {
    const float* x    = (const float*)d_in[0];  // (B, J, I)
    const float* w    = (const float*)d_in[1];  // (K, J, I)
    const float* bias = (const float*)d_in[2];  // (K, J, 1)
    float* out = (float*)d_out;                 // (B, K, I)

    float* cw2 = (float*)d_ws;                  // 2 MB, blocked layout
    float* sp  = cw2 + (size_t)K * J * B;       // JC*B*K*I floats (8 MB)

    hipLaunchKernelGGL(k1_mfma,  dim3(512),  dim3(64),  0, stream, x, w, bias, cw2);
    hipLaunchKernelGGL(k3_wsum,  dim3(1024), dim3(256), 0, stream, x, w, cw2, sp);
    hipLaunchKernelGGL(k4_squash, dim3(256), dim3(256), 0, stream, sp, out);
}

// Round 6
// 26.716 us; speedup vs baseline: 4.5733x; 4.5733x over previous
//
#include <hip/hip_runtime.h>
#include <math.h>

#define B 64
#define K 16
#define J 512
#define I 128
#define SCALE 0.08838834764831845f /* 1/sqrt(128) */
#define EPSF 1e-20f
#define JC 16  /* j-chunks */
#define JCW 32 /* J / JC */

typedef __attribute__((ext_vector_type(8))) short short8;
typedef __attribute__((ext_vector_type(4))) float f32x4;

static __device__ __forceinline__ unsigned f2bf(float f) {
    union { float f; unsigned u; } v; v.f = f;
    return (v.u + 0x7FFFu + ((v.u >> 16) & 1u)) >> 16;  // RNE to bf16
}

// ---------------------------------------------------------------------------
// K1: logits via bf16 MFMA + softmax over batch + bias.
// One wave per j. XCD-aligned j (XCD c owns j in [64c,64c+64)) so k1
// pre-warms exactly the L2 slice its XCD's k3 blocks read.
// Output blocked: cw2[kt][bt][j][kk][bb] for coalesced k3 staging.
// ---------------------------------------------------------------------------
__global__ __launch_bounds__(64) void k1_mfma(const float* __restrict__ x,
                                              const float* __restrict__ w,
                                              const float* __restrict__ bias,
                                              float* __restrict__ cw2) {
    __shared__ __align__(16) char lds[80 * 256];  // lx[64][256] + lw[16][256]
    char* lx = lds;
    char* lw = lds + 64 * 256;

    const int raw = blockIdx.x;                  // 0..511
    const int j = (raw & 7) * 64 + (raw >> 3);   // XCD-aligned j
    const int l = threadIdx.x;
    const int q = l & 31, hi = l >> 5;

    const float4* xs = (const float4*)x;
    const float4* wsrc = (const float4*)w;

#pragma unroll
    for (int it = 0; it < 32; ++it) {
        int b = it * 2 + hi;
        float4 v = xs[((size_t)b * J + j) * 32 + q];
        uint2 u;
        u.x = f2bf(v.x * v.x) | (f2bf(v.y * v.y) << 16);
        u.y = f2bf(v.z * v.z) | (f2bf(v.w * v.w) << 16);
        *(uint2*)(lx + b * 256 + ((q * 8) ^ ((b & 7) << 4))) = u;
    }
#pragma unroll
    for (int it = 0; it < 8; ++it) {
        int k = it * 2 + hi;
        float4 v = wsrc[((size_t)k * J + j) * 32 + q];
        uint2 u;
        u.x = f2bf(v.x * v.x) | (f2bf(v.y * v.y) << 16);
        u.y = f2bf(v.z * v.z) | (f2bf(v.w * v.w) << 16);
        *(uint2*)(lw + k * 256 + ((q * 8) ^ ((k & 7) << 4))) = u;
    }
    __syncthreads();

    const int g = l >> 4, n = l & 15;
    f32x4 acc[4];
#pragma unroll
    for (int t = 0; t < 4; ++t) acc[t] = (f32x4){0.f, 0.f, 0.f, 0.f};

#pragma unroll
    for (int s = 0; s < 4; ++s) {
        const int colb = s * 64 + g * 16;
        short8 af = *(const short8*)(lw + n * 256 + (colb ^ ((n & 7) << 4)));
#pragma unroll
        for (int t = 0; t < 4; ++t) {
            int row = t * 16 + n;
            short8 bf = *(const short8*)(lx + row * 256 + (colb ^ ((row & 7) << 4)));
            acc[t] = __builtin_amdgcn_mfma_f32_16x16x32_bf16(af, bf, acc[t], 0, 0, 0);
        }
    }

    // lane holds c_raw[m=g*4+r][b=t*16+n] in acc[t][r]
#pragma unroll
    for (int r = 0; r < 4; ++r) {
        float s0 = acc[0][r] * SCALE, s1 = acc[1][r] * SCALE;
        float s2 = acc[2][r] * SCALE, s3 = acc[3][r] * SCALE;
        float mx = fmaxf(fmaxf(s0, s1), fmaxf(s2, s3));
#pragma unroll
        for (int msk = 1; msk <= 8; msk <<= 1) mx = fmaxf(mx, __shfl_xor(mx, msk, 64));
        float e0 = expf(s0 - mx), e1 = expf(s1 - mx);
        float e2 = expf(s2 - mx), e3 = expf(s3 - mx);
        float sum = e0 + e1 + e2 + e3;
#pragma unroll
        for (int msk = 1; msk <= 8; msk <<= 1) sum += __shfl_xor(sum, msk, 64);
        float inv = 1.f / sum;
        int m = g * 4 + r;
        float bi = bias[m * J + j];
        // cw2[kt=g][bt=t*4+(n>>2)][j][kk=r][bb=n&3]
        size_t base = (size_t)g * 131072 + (size_t)j * 16 + r * 4 + (n & 3);
        cw2[base + (size_t)(0 + (n >> 2)) * 8192]  = e0 * inv + bi;
        cw2[base + (size_t)(4 + (n >> 2)) * 8192]  = e1 * inv + bi;
        cw2[base + (size_t)(8 + (n >> 2)) * 8192]  = e2 * inv + bi;
        cw2[base + (size_t)(12 + (n >> 2)) * 8192] = e3 * inv + bi;
    }
}

// ---------------------------------------------------------------------------
// K3: sp[jh][b][k][i] = sum_{j in chunk jh} x*w*c.
// 1024 blocks = 16 bt x 4 kt x 16 jh, XCD-aligned (XCD c owns chunks
// {2c,2c+1} = j in [64c,64c+64)). Thread: 4b x 4k x float4 register tile
// (all indices COMPILE-TIME; runtime-indexing acc demotes it to scratch —
// that was rounds 4/5's 110 us regression: VGPR=52, 399 MB scratch writes).
// Coalesced c staging; shfl_xor(32) pre-reduce; one static LDS round.
// ---------------------------------------------------------------------------
__global__ __launch_bounds__(256) void k3_wsum(const float* __restrict__ x,
                                               const float* __restrict__ w,
                                               const float* __restrict__ cw2,
                                               float* __restrict__ sp) {
    __shared__ float cl[JCW * 16];                     // 2 KB [jl][kk][bb]
    __shared__ __align__(16) float4 red[4 * 16 * 32];  // 32 KB [w][slot][iq]

    const int raw = blockIdx.x;                 // 0..1023
    const int swz = (raw & 7) * 128 + (raw >> 3);
    const int kt = swz & 3, bt = (swz >> 2) & 15, jh = swz >> 6;
    const int j0 = jh * JCW, b0 = bt * 4, k0 = kt * 4;

    const int iq = threadIdx.x & 31;
    const int js = threadIdx.x >> 5;

    if (threadIdx.x < 128)
        ((float4*)cl)[threadIdx.x] =
            ((const float4*)(cw2 + (size_t)kt * 131072 + (size_t)bt * 8192 +
                             (size_t)j0 * 16))[threadIdx.x];
    __syncthreads();

    float4 acc[4][4];
#pragma unroll
    for (int bb = 0; bb < 4; ++bb)
#pragma unroll
        for (int kk = 0; kk < 4; ++kk) acc[bb][kk] = make_float4(0.f, 0.f, 0.f, 0.f);

#pragma unroll
    for (int it = 0; it < 4; ++it) {
        int j = j0 + js + it * 8;
        float4 xv[4], wv[4];
#pragma unroll
        for (int bb = 0; bb < 4; ++bb)
            xv[bb] = *(const float4*)(x + ((size_t)(b0 + bb) * J + j) * I + iq * 4);
#pragma unroll
        for (int kk = 0; kk < 4; ++kk)
            wv[kk] = *(const float4*)(w + ((size_t)(k0 + kk) * J + j) * I + iq * 4);
        const float* cj = cl + (js + it * 8) * 16;
#pragma unroll
        for (int kk = 0; kk < 4; ++kk) {
#pragma unroll
            for (int bb = 0; bb < 4; ++bb) {
                float c = cj[kk * 4 + bb];
                acc[bb][kk].x = fmaf(xv[bb].x * wv[kk].x, c, acc[bb][kk].x);
                acc[bb][kk].y = fmaf(xv[bb].y * wv[kk].y, c, acc[bb][kk].y);
                acc[bb][kk].z = fmaf(xv[bb].z * wv[kk].z, c, acc[bb][kk].z);
                acc[bb][kk].w = fmaf(xv[bb].w * wv[kk].w, c, acc[bb][kk].w);
            }
        }
    }

    // reduce across the two js-halves of each wave (lanes end with the sum)
#pragma unroll
    for (int bb = 0; bb < 4; ++bb)
#pragma unroll
        for (int kk = 0; kk < 4; ++kk) {
            acc[bb][kk].x += __shfl_xor(acc[bb][kk].x, 32, 64);
            acc[bb][kk].y += __shfl_xor(acc[bb][kk].y, 32, 64);
            acc[bb][kk].z += __shfl_xor(acc[bb][kk].z, 32, 64);
            acc[bb][kk].w += __shfl_xor(acc[bb][kk].w, 32, 64);
        }

    // low half-wave writes all 16 slots with COMPILE-TIME acc indices
    const int wv4 = threadIdx.x >> 6;
    if ((threadIdx.x & 32) == 0) {
#pragma unroll
        for (int bb = 0; bb < 4; ++bb)
#pragma unroll
            for (int kk = 0; kk < 4; ++kk)
                red[(wv4 * 16 + bb * 4 + kk) * 32 + iq] = acc[bb][kk];
    }
    __syncthreads();

#pragma unroll
    for (int rep = 0; rep < 2; ++rep) {
        int slot = rep * 8 + (threadIdx.x >> 5);
        float4 a = red[(0 * 16 + slot) * 32 + iq];
        float4 b = red[(1 * 16 + slot) * 32 + iq];
        float4 c = red[(2 * 16 + slot) * 32 + iq];
        float4 d = red[(3 * 16 + slot) * 32 + iq];
        float4 v = make_float4(a.x + b.x + c.x + d.x, a.y + b.y + c.y + d.y,
                               a.z + b.z + c.z + d.z, a.w + b.w + c.w + d.w);
        int bb = slot >> 2, kk = slot & 3;
        *(float4*)(sp + (((size_t)jh * B + b0 + bb) * K + k0 + kk) * I + iq * 4) = v;
    }
}

// ---------------------------------------------------------------------------
// K4: wave per (b,k): sum 16 partials, squash over i, write out. No LDS.
// ---------------------------------------------------------------------------
__global__ __launch_bounds__(256) void k4_squash(const float* __restrict__ sp,
                                                 float* __restrict__ out) {
    const int wv = threadIdx.x >> 6;
    const int lane = threadIdx.x & 63;
    const int bk = blockIdx.x * 4 + wv;       // 0..1023
    const int b = bk >> 4, k = bk & 15;

    float s0 = 0.f, s1 = 0.f;
#pragma unroll
    for (int p = 0; p < JC; ++p) {
        float2 v = *(const float2*)(sp + (((size_t)p * B + b) * K + k) * I + lane * 2);
        s0 += v.x; s1 += v.y;
    }
    float q = s0 * s0 + s1 * s1;
#pragma unroll
    for (int m = 32; m >= 1; m >>= 1) q += __shfl_xor(q, m, 64);

    float n = sqrtf(q);
    float factor = (1.0f - 1.0f / (expf(n) + EPSF)) / (n + EPSF);
    float2 o = make_float2(s0 * factor, s1 * factor);
    *(float2*)(out + ((size_t)b * K + k) * I + lane * 2) = o;
}

// ---------------------------------------------------------------------------
extern "C" void kernel_launch(void* const* d_in, const int* in_sizes, int n_in,
                              void* d_out, int out_size, void* d_ws, size_t ws_size,
                              hipStream_t stream) {
    const float* x    = (const float*)d_in[0];  // (B, J, I)
    const float* w    = (const float*)d_in[1];  // (K, J, I)
    const float* bias = (const float*)d_in[2];  // (K, J, 1)
    float* out = (float*)d_out;                 // (B, K, I)

    float* cw2 = (float*)d_ws;                  // 2 MB, blocked layout
    float* sp  = cw2 + (size_t)K * J * B;       // JC*B*K*I floats (8 MB)

    hipLaunchKernelGGL(k1_mfma,  dim3(512),  dim3(64),  0, stream, x, w, bias, cw2);
    hipLaunchKernelGGL(k3_wsum,  dim3(1024), dim3(256), 0, stream, x, w, cw2, sp);
    hipLaunchKernelGGL(k4_squash, dim3(256), dim3(256), 0, stream, sp, out);
}